// Round 17
// baseline (258.604 us; speedup 1.0000x reference)
//
#include <hip/hip_runtime.h>

// ---------------------------------------------------------------------------
// GPT-2 block: [transpose+LN1 fused] -> QKV GEMM (scatter q/k/vT) -> causal
// flash attn -> proj+res -> LN2 -> FC+GELU (256^2 counted-vmcnt) -> proj+res
// B=4 T=2048 C=768 H=12 HD=64. MFMA bf16, fp32 accum.
// r16 base; FC uses 256x256x64 tile, 512 thr, depth-2 prefetch with counted
// vmcnt(8) across raw barriers (loads stay in flight; 2x FLOP/staged-byte).
// ---------------------------------------------------------------------------

typedef unsigned short u16;
typedef unsigned int u32;
typedef __attribute__((ext_vector_type(8))) short short8;   // 8 bf16 = 4 VGPR
typedef __attribute__((ext_vector_type(4))) float f32x4;
typedef __attribute__((ext_vector_type(16))) float f32x16;  // 32x32 MFMA C/D

__device__ __forceinline__ u16 f2bf(float f) {
    union { float f; unsigned u; } v; v.f = f;
    unsigned u = v.u;
    unsigned r = (u + 0x7FFFu + ((u >> 16) & 1u)) >> 16;
    return (u16)r;
}
__device__ __forceinline__ float bf2f(u16 h) {
    union { u32 u; float f; } v; v.u = ((u32)h) << 16;
    return v.f;
}

__device__ __forceinline__ u32 cvtpk_bf16(float lo, float hi) {
    u32 r;
    asm("v_cvt_pk_bf16_f32 %0, %1, %2" : "=v"(r) : "v"(lo), "v"(hi));
    return r;
}

// async global->LDS, 16B per lane. dest must be wave-uniform base + lane*16.
__device__ __forceinline__ void gld16(const u16* g, u16* l) {
    __builtin_amdgcn_global_load_lds(
        (const __attribute__((address_space(1))) void*)g,
        (__attribute__((address_space(3))) void*)l, 16, 0, 0);
}

// gelu_tanh(v) = v * sigmoid(2*0.79788456*(v + 0.044715 v^3))
__device__ __forceinline__ float gelu_fast(float v) {
    float t = v * v;
    float z2n = v * (-2.3022078f - 0.10294376f * t);   // -2z*log2(e)
    float e = __builtin_amdgcn_exp2f(z2n);             // e^{-2z}
    return v * __builtin_amdgcn_rcpf(1.0f + e);
}

// ---------------------------------------------------------------------------
// LayerNorm core: 3 values/thread -> bf16 out, 256 threads.
// ---------------------------------------------------------------------------
__device__ __forceinline__ void ln_core(float v0, float v1, float v2,
                                        const float* __restrict__ s,
                                        const float* __restrict__ b,
                                        u16* __restrict__ orow,
                                        float* red, int tid) {
    float sum = v0 + v1 + v2;
    float sq = v0 * v0 + v1 * v1 + v2 * v2;
#pragma unroll
    for (int off = 32; off; off >>= 1) {
        sum += __shfl_down(sum, off);
        sq += __shfl_down(sq, off);
    }
    int wid = tid >> 6, lane = tid & 63;
    if (lane == 0) { red[wid] = sum; red[4 + wid] = sq; }
    __syncthreads();
    if (tid == 0) {
        float s4 = red[0] + red[1] + red[2] + red[3];
        float q4 = red[4] + red[5] + red[6] + red[7];
        red[0] = s4 * (1.0f / 768.0f);
        red[1] = q4 * (1.0f / 768.0f);
    }
    __syncthreads();
    float mean = red[0];
    float var = red[1] - mean * mean;
    float rstd = rsqrtf(var + 1e-5f);
    orow[tid]       = f2bf((v0 - mean) * rstd * s[tid]       + b[tid]);
    orow[tid + 256] = f2bf((v1 - mean) * rstd * s[tid + 256] + b[tid + 256]);
    orow[tid + 512] = f2bf((v2 - mean) * rstd * s[tid + 512] + b[tid + 512]);
}

// ---------------------------------------------------------------------------
// Fused: weight transpose+convert (blocks [0,6912)) + LN1 (blocks [6912,15104)).
// ---------------------------------------------------------------------------
__global__ void pre_kernel(const float* __restrict__ w_attn, u16* __restrict__ wT_attn,
                           const float* __restrict__ w_o,    u16* __restrict__ wT_o,
                           const float* __restrict__ w_fc,   u16* __restrict__ wT_fc,
                           const float* __restrict__ w_proj, u16* __restrict__ wT_proj,
                           const float* __restrict__ x, const float* __restrict__ ln1_s,
                           const float* __restrict__ ln1_b, u16* __restrict__ h) {
    __shared__ float t[32][33];
    __shared__ float red[8];
    int tile = blockIdx.x;
    int tid = threadIdx.x;
    if (tile >= 6912) {
        int row = tile - 6912;
        const float* xr = x + (size_t)row * 768;
        ln_core(xr[tid], xr[tid + 256], xr[tid + 512], ln1_s, ln1_b,
                h + (size_t)row * 768, red, tid);
        return;
    }
    const float* w; u16* wt; int N; int idx;
    if (tile < 1728)      { w = w_attn; wt = wT_attn; N = 2304; idx = tile; }
    else if (tile < 2304) { w = w_o;    wt = wT_o;    N = 768;  idx = tile - 1728; }
    else if (tile < 4608) { w = w_fc;   wt = wT_fc;   N = 3072; idx = tile - 2304; }
    else                  { w = w_proj; wt = wT_proj; N = 768;  idx = tile - 4608; }
    int K = (tile >= 4608) ? 3072 : 768;
    int nx = N / 32;
    int n0 = (idx % nx) * 32, k0 = (idx / nx) * 32;
    int tx = tid & 31, ty = tid >> 5;  // 32 x 8
#pragma unroll
    for (int i = 0; i < 4; i++)
        t[ty + 8 * i][tx] = w[(size_t)(k0 + ty + 8 * i) * N + n0 + tx];
    __syncthreads();
#pragma unroll
    for (int i = 0; i < 4; i++)
        wt[(size_t)(n0 + ty + 8 * i) * K + k0 + tx] = f2bf(t[tx][ty + 8 * i]);
}

// ---------------------------------------------------------------------------
// LN2: bf16 input [8192][768] -> bf16 out
// ---------------------------------------------------------------------------
__global__ void ln_bf16_kernel(const u16* __restrict__ x, const float* __restrict__ s,
                               const float* __restrict__ b, u16* __restrict__ out) {
    __shared__ float red[8];
    int row = blockIdx.x;
    int tid = threadIdx.x;
    const u16* xr = x + (size_t)row * 768;
    ln_core(bf2f(xr[tid]), bf2f(xr[tid + 256]), bf2f(xr[tid + 512]),
            s, b, out + (size_t)row * 768, red, tid);
}

// ---------------------------------------------------------------------------
// GEMM (r9/r14 structure): out = act(A @ Wt^T + bias [+ res])
// OUTMODE: 0 = fp32 out, 1 = bf16 out, 2 = QKV scatter. RESBF: res is bf16.
// BM = 128 (4x4 frags) or 64 (2x4). BN=128 BK=64. 256 thr = 4 waves.
// 2-phase dbuf: stage tile t+1, compute tile t, one __syncthreads per tile.
// ---------------------------------------------------------------------------
template <int GELU, int RES, int RESBF, int OUTMODE, int BM>
__global__ __launch_bounds__(256) void gemm_kernel(
    const u16* __restrict__ A, const u16* __restrict__ Wt,
    const float* __restrict__ bias, const void* __restrict__ res,
    void* __restrict__ out, int M, int N, int K,
    u16* __restrict__ qbuf, u16* __restrict__ kbuf, u16* __restrict__ vbuf) {
    constexpr int FM = BM / 32;          // m-frags per wave (4 or 2)
    constexpr int SA = BM / 32;          // A stage rounds (4 or 2)
    constexpr int WR = BM / 2;           // wave row stride
    __shared__ __align__(16) u16 lA[2][BM * 64];
    __shared__ __align__(16) u16 lB[2][128 * 64];
    int m0 = blockIdx.x * BM, n0 = blockIdx.y * 128;
    int tid = threadIdx.x;
    int wid = tid >> 6, lane = tid & 63;
    int wr = wid >> 1, wc = wid & 1;
    int l15 = lane & 15, lhi = lane >> 4;

    const u16* aptr[SA];
    const u16* bptr[4];
#pragma unroll
    for (int s = 0; s < SA; s++) {
        int u = s * 256 + tid;
        int row = u >> 3;
        int c8 = (u & 7) ^ (row & 7);
        aptr[s] = A + (size_t)(m0 + row) * K + c8 * 8;
    }
#pragma unroll
    for (int s = 0; s < 4; s++) {
        int u = s * 256 + tid;
        int row = u >> 3;
        int c8 = (u & 7) ^ (row & 7);
        bptr[s] = Wt + (size_t)(n0 + row) * K + c8 * 8;
    }

    f32x4 acc[FM][4];
#pragma unroll
    for (int i = 0; i < FM; i++)
#pragma unroll
        for (int j = 0; j < 4; j++) acc[i][j] = (f32x4)0.0f;

    // prologue: stage tile 0 into buffer 0
#pragma unroll
    for (int s = 0; s < SA; s++) gld16(aptr[s], &lA[0][(s * 256 + tid) * 8]);
#pragma unroll
    for (int s = 0; s < 4; s++) gld16(bptr[s], &lB[0][(s * 256 + tid) * 8]);
    __syncthreads();

    int KT = K >> 6;
    int cur = 0;
    for (int t = 0; t < KT; t++) {
        if (t + 1 < KT) {
            int ko = (t + 1) << 6;
#pragma unroll
            for (int s = 0; s < SA; s++) gld16(aptr[s] + ko, &lA[cur ^ 1][(s * 256 + tid) * 8]);
#pragma unroll
            for (int s = 0; s < 4; s++) gld16(bptr[s] + ko, &lB[cur ^ 1][(s * 256 + tid) * 8]);
        }
        short8 af[2][FM], bfr[2][4];
#pragma unroll
        for (int ks = 0; ks < 2; ks++) {
#pragma unroll
            for (int f = 0; f < FM; f++) {
                int ra = wr * WR + f * 16 + l15;
                af[ks][f] = *(const short8*)&lA[cur][ra * 64 + (((ks * 4 + lhi) ^ (ra & 7)) << 3)];
            }
#pragma unroll
            for (int f = 0; f < 4; f++) {
                int rb = wc * 64 + f * 16 + l15;
                bfr[ks][f] = *(const short8*)&lB[cur][rb * 64 + (((ks * 4 + lhi) ^ (rb & 7)) << 3)];
            }
        }
        __builtin_amdgcn_s_setprio(1);
#pragma unroll
        for (int ks = 0; ks < 2; ks++)
#pragma unroll
            for (int fm = 0; fm < FM; fm++)
#pragma unroll
                for (int fn = 0; fn < 4; fn++)
                    acc[fm][fn] = __builtin_amdgcn_mfma_f32_16x16x32_bf16(
                        af[ks][fm], bfr[ks][fn], acc[fm][fn], 0, 0, 0);
        __builtin_amdgcn_s_setprio(0);
        __syncthreads();   // drains vmcnt(0): next tile ready; buf[cur] reusable
        cur ^= 1;
    }

    if (OUTMODE == 2) {
        int region = n0 / 768;
#pragma unroll
        for (int fm = 0; fm < FM; fm++)
#pragma unroll
            for (int fn = 0; fn < 4; fn++) {
                int col = n0 + wc * 64 + fn * 16 + l15;
                float bv = bias[col];
                int c = col - region * 768;
                int h = c >> 6, d = c & 63;
                if (region == 2) {
                    // v: [bh][d][t] — 4 consecutive t per thread -> one 8B store
                    int row0 = m0 + wr * WR + fm * 16 + lhi * 4;
                    int bb = row0 >> 11, t0 = row0 & 2047;
                    size_t bh = (size_t)bb * 12 + h;
                    union { u16 a[4]; uint2 v; } pk;
#pragma unroll
                    for (int r = 0; r < 4; r++) pk.a[r] = f2bf(acc[fm][fn][r] + bv);
                    *(uint2*)(&vbuf[(bh * 64 + d) * 2048 + t0]) = pk.v;
                } else {
#pragma unroll
                    for (int r = 0; r < 4; r++) {
                        int row = m0 + wr * WR + fm * 16 + lhi * 4 + r;
                        int bb = row >> 11, t = row & 2047;
                        u16 val = f2bf(acc[fm][fn][r] + bv);
                        size_t bh = (size_t)bb * 12 + h;
                        if (region == 0) qbuf[(bh * 2048 + t) * 64 + d] = val;
                        else             kbuf[(bh * 2048 + t) * 64 + d] = val;
                    }
                }
            }
    } else {
#pragma unroll
        for (int fm = 0; fm < FM; fm++)
#pragma unroll
            for (int fn = 0; fn < 4; fn++) {
                int col = n0 + wc * 64 + fn * 16 + l15;
                float bv = bias[col];
#pragma unroll
                for (int r = 0; r < 4; r++) {
                    int row = m0 + wr * WR + fm * 16 + lhi * 4 + r;
                    float v = acc[fm][fn][r] + bv;
                    if (RES) {
                        if (RESBF) v += bf2f(((const u16*)res)[(size_t)row * N + col]);
                        else       v += ((const float*)res)[(size_t)row * N + col];
                    }
                    if (GELU) v = gelu_fast(v);
                    if (OUTMODE == 1)
                        ((u16*)out)[(size_t)row * N + col] = f2bf(v);
                    else
                        ((float*)out)[(size_t)row * N + col] = v;
                }
            }
    }
}

// ---------------------------------------------------------------------------
// 256x256x64 GEMM, 512 thr = 8 waves (2M x 4N), wave tile 128x64.
// Depth-2 prefetch, counted vmcnt(8) + raw barriers (r7 scheme, correct):
// tile t's 8 loads guaranteed done when only t+1's 8 remain outstanding.
// LDS 128 KB -> 1 block/CU; loads stay in flight across both barriers.
// bf16 out + optional GELU. Used for FC (grid 32x12).
// ---------------------------------------------------------------------------
template <int GELU>
__global__ __launch_bounds__(512) void gemm256_kernel(
    const u16* __restrict__ A, const u16* __restrict__ Wt,
    const float* __restrict__ bias, u16* __restrict__ out,
    int M, int N, int K) {
    __shared__ __align__(16) u16 lA[2][256 * 64];   // 64 KB
    __shared__ __align__(16) u16 lB[2][256 * 64];   // 64 KB
    int m0 = blockIdx.x * 256, n0 = blockIdx.y * 256;
    int tid = threadIdx.x;
    int wid = tid >> 6, lane = tid & 63;
    int wr = wid >> 2, wc = wid & 3;        // 2 x 4
    int l15 = lane & 15, lhi = lane >> 4;

    const u16* aptr[4];
    const u16* bptr[4];
#pragma unroll
    for (int s = 0; s < 4; s++) {
        int u = s * 512 + tid;
        int row = u >> 3;
        int c8 = (u & 7) ^ (row & 7);
        aptr[s] = A + (size_t)(m0 + row) * K + c8 * 8;
        bptr[s] = Wt + (size_t)(n0 + row) * K + c8 * 8;
    }

    auto stage = [&](int t, int buf) {
        int ko = t << 6;
#pragma unroll
        for (int s = 0; s < 4; s++) gld16(aptr[s] + ko, &lA[buf][(s * 512 + tid) * 8]);
#pragma unroll
        for (int s = 0; s < 4; s++) gld16(bptr[s] + ko, &lB[buf][(s * 512 + tid) * 8]);
    };

    f32x4 acc[8][4];
#pragma unroll
    for (int i = 0; i < 8; i++)
#pragma unroll
        for (int j = 0; j < 4; j++) acc[i][j] = (f32x4)0.0f;

    int KT = K >> 6;
    stage(0, 0);
    stage(1, 1);

    int cur = 0;
    for (int t = 0; t < KT; t++) {
        if (t + 1 < KT) asm volatile("s_waitcnt vmcnt(8)" ::: "memory");
        else            asm volatile("s_waitcnt vmcnt(0)" ::: "memory");
        __builtin_amdgcn_s_barrier();
        __builtin_amdgcn_sched_barrier(0);

#pragma unroll
        for (int ks = 0; ks < 2; ks++) {
            short8 af[8], bfr[4];
#pragma unroll
            for (int f = 0; f < 8; f++) {
                int ra = wr * 128 + f * 16 + l15;
                af[f] = *(const short8*)&lA[cur][ra * 64 + (((ks * 4 + lhi) ^ (ra & 7)) << 3)];
            }
#pragma unroll
            for (int f = 0; f < 4; f++) {
                int rb = wc * 64 + f * 16 + l15;
                bfr[f] = *(const short8*)&lB[cur][rb * 64 + (((ks * 4 + lhi) ^ (rb & 7)) << 3)];
            }
            __builtin_amdgcn_s_setprio(1);
#pragma unroll
            for (int fm = 0; fm < 8; fm++)
#pragma unroll
                for (int fn = 0; fn < 4; fn++)
                    acc[fm][fn] = __builtin_amdgcn_mfma_f32_16x16x32_bf16(
                        af[fm], bfr[fn], acc[fm][fn], 0, 0, 0);
            __builtin_amdgcn_s_setprio(0);
        }
        __builtin_amdgcn_sched_barrier(0);
        __builtin_amdgcn_s_barrier();       // all waves done reading buf[cur]
        __builtin_amdgcn_sched_barrier(0);
        if (t + 2 < KT) stage(t + 2, cur);  // refill freed buffer (stays in flight)
        cur ^= 1;
    }

#pragma unroll
    for (int fm = 0; fm < 8; fm++)
#pragma unroll
        for (int fn = 0; fn < 4; fn++) {
            int col = n0 + wc * 64 + fn * 16 + l15;
            float bv = bias[col];
#pragma unroll
            for (int r = 0; r < 4; r++) {
                int row = m0 + wr * 128 + fm * 16 + lhi * 4 + r;
                float v = acc[fm][fn][r] + bv;
                if (GELU) v = gelu_fast(v);
                out[(size_t)row * N + col] = f2bf(v);
            }
        }
}

// ---------------------------------------------------------------------------
// Causal flash attention (r12/r14 structure): swapped-QK^T 32x32, 2-phase
// K/V staging, online-max softmax w/ defer-rescale, MFMA row-sums, setprio.
// 128 threads = 2 waves x 32 q-rows, QBLK=64, 1536 blocks.
// q/k: bf16 [bh][t][64]; vT: bf16 [bh][64][t]. ctx: bf16 [b*T][768].
// ---------------------------------------------------------------------------
__global__ __launch_bounds__(128) void attn_kernel(const u16* __restrict__ qbuf,
                                                   const u16* __restrict__ kbuf,
                                                   const u16* __restrict__ vbuf,
                                                   u16* __restrict__ ctx) {
    int bid = blockIdx.x;
    int qt = 31 - (bid / 48);        // heavy tiles first
    int bh = bid % 48;
    int b = bh / 12, h = bh % 12;
    int q0 = qt * 64;
    int tid = threadIdx.x, wid = tid >> 6, lane = tid & 63;
    int l31 = lane & 31, hi = lane >> 5;

    __shared__ __align__(16) u16 lK[2][64 * 64];   // [key][d] swizzled
    __shared__ __align__(16) u16 lV[2][64 * 64];   // [d][key] swizzled

    const size_t bhT = (size_t)bh * 2048;

    const u16* kp[4];
    const u16* vp[4];
#pragma unroll
    for (int s = 0; s < 4; s++) {
        int u = s * 128 + tid;
        int row = u >> 3;
        int c8 = (u & 7) ^ (row & 7);
        kp[s] = kbuf + (bhT + row) * 64 + c8 * 8;                    // + k0*64
        vp[s] = vbuf + ((size_t)bh * 64 + row) * 2048 + c8 * 8;      // + k0
    }

    // Q B-fragments: b[j] = Q[q=l31][d = ks*16 + 8*hi + j]
    int qrow = q0 + wid * 32 + l31;
    short8 bq[4];
#pragma unroll
    for (int ks = 0; ks < 4; ks++)
        bq[ks] = *(const short8*)(qbuf + (bhT + qrow) * 64 + ks * 16 + hi * 8);

    short8 ones;
#pragma unroll
    for (int j = 0; j < 8; j++) ones[j] = (short)0x3F80;  // bf16 1.0

    f32x16 oacc[2], sacc;
#pragma unroll
    for (int dt = 0; dt < 2; dt++) oacc[dt] = (f32x16)0.0f;
    sacc = (f32x16)0.0f;
    float mb = -1e30f;
    const float C2 = 0.125f * 1.44269504089f;
    const float THR = 11.55f;        // 8 nats in log2
    int myq = q0 + wid * 32 + l31;

    int nt = qt + 1;
#pragma unroll
    for (int s = 0; s < 4; s++) gld16(kp[s], &lK[0][(s * 128 + tid) * 8]);
#pragma unroll
    for (int s = 0; s < 4; s++) gld16(vp[s], &lV[0][(s * 128 + tid) * 8]);
    __syncthreads();

    int cur = 0;
    for (int t = 0; t < nt; t++) {
        int k0 = t * 64;
        if (t + 1 < nt) {
            int kn = (t + 1) * 64;
#pragma unroll
            for (int s = 0; s < 4; s++) gld16(kp[s] + (size_t)kn * 64, &lK[cur ^ 1][(s * 128 + tid) * 8]);
#pragma unroll
            for (int s = 0; s < 4; s++) gld16(vp[s] + kn, &lV[cur ^ 1][(s * 128 + tid) * 8]);
        }
        {
            f32x16 sa[2];
#pragma unroll
            for (int kt = 0; kt < 2; kt++) sa[kt] = (f32x16)0.0f;
            __builtin_amdgcn_s_setprio(1);
#pragma unroll
            for (int kt = 0; kt < 2; kt++) {
                int rk = kt * 32 + l31;
#pragma unroll
                for (int ks = 0; ks < 4; ks++) {
                    short8 ak = *(const short8*)&lK[cur][rk * 64 + (((ks * 2 + hi) ^ (rk & 7)) << 3)];
                    sa[kt] = __builtin_amdgcn_mfma_f32_32x32x16_bf16(ak, bq[ks], sa[kt], 0, 0, 0);
                }
            }
            __builtin_amdgcn_s_setprio(0);
            if (k0 + 63 > q0 + wid * 32) {
#pragma unroll
                for (int kt = 0; kt < 2; kt++)
#pragma unroll
                    for (int r = 0; r < 16; r++) {
                        int key = k0 + kt * 32 + (r & 3) + 8 * (r >> 2) + 4 * hi;
                        if (key > myq) sa[kt][r] = -1e30f;
                    }
            }
            float tmax = -1e30f;
#pragma unroll
            for (int kt = 0; kt < 2; kt++)
#pragma unroll
                for (int r = 0; r < 16; r += 2)
                    tmax = fmaxf(tmax, fmaxf(sa[kt][r], sa[kt][r + 1]));  // -> v_max3
            tmax = fmaxf(tmax, __shfl_xor(tmax, 32));
            float tmb = tmax * C2;
            if (__any(tmb > mb + THR)) {
                float mbn = fmaxf(mb, tmb);
                float corr = __builtin_amdgcn_exp2f(mb - mbn);
#pragma unroll
                for (int r = 0; r < 16; r++) {
                    int qm = (r & 3) + 8 * (r >> 2) + 4 * hi;
                    float c = __shfl(corr, qm);
                    oacc[0][r] *= c;
                    oacc[1][r] *= c;
                    sacc[r] *= c;
                }
                mb = mbn;
            }
#pragma unroll
            for (int kt = 0; kt < 2; kt++)
#pragma unroll
                for (int r = 0; r < 16; r++)
                    sa[kt][r] = __builtin_amdgcn_exp2f(fmaf(sa[kt][r], C2, -mb));
            short8 pa[4];
#pragma unroll
            for (int kt = 0; kt < 2; kt++)
#pragma unroll
                for (int ks2 = 0; ks2 < 2; ks2++) {
                    int base = ks2 * 8;
                    u32 A0 = cvtpk_bf16(sa[kt][base + 0], sa[kt][base + 1]);
                    u32 B0 = cvtpk_bf16(sa[kt][base + 4], sa[kt][base + 5]);
                    u32 A1 = cvtpk_bf16(sa[kt][base + 2], sa[kt][base + 3]);
                    u32 B1 = cvtpk_bf16(sa[kt][base + 6], sa[kt][base + 7]);
                    u32 A0s = (u32)__shfl_xor((int)A0, 32);
                    u32 B0s = (u32)__shfl_xor((int)B0, 32);
                    u32 A1s = (u32)__shfl_xor((int)A1, 32);
                    u32 B1s = (u32)__shfl_xor((int)B1, 32);
                    union { u32 u[4]; short8 s; } w;
                    w.u[0] = hi ? B0s : A0;
                    w.u[1] = hi ? B1s : A1;
                    w.u[2] = hi ? B0 : A0s;
                    w.u[3] = hi ? B1 : A1s;
                    pa[kt * 2 + ks2] = w.s;
                }
            __builtin_amdgcn_s_setprio(1);
#pragma unroll
            for (int kt = 0; kt < 2; kt++)
#pragma unroll
                for (int ks2 = 0; ks2 < 2; ks2++) {
                    short8 ap = pa[kt * 2 + ks2];
#pragma unroll
                    for (int dt = 0; dt < 2; dt++) {
                        int rd = dt * 32 + l31;
                        short8 bv = *(const short8*)&lV[cur][rd * 64 + (((kt * 4 + ks2 * 2 + hi) ^ (rd & 7)) << 3)];
                        oacc[dt] = __builtin_amdgcn_mfma_f32_32x32x16_bf16(ap, bv, oacc[dt], 0, 0, 0);
                    }
                    sacc = __builtin_amdgcn_mfma_f32_32x32x16_bf16(ap, ones, sacc, 0, 0, 0);
                }
            __builtin_amdgcn_s_setprio(0);
        }
        __syncthreads();
        cur ^= 1;
    }
    const size_t rowb = (size_t)b * 2048;
#pragma unroll
    for (int r = 0; r < 16; r++) {
        float ir = __builtin_amdgcn_rcpf(sacc[r]);
        int qm = (r & 3) + 8 * (r >> 2) + 4 * hi;
        int row = q0 + wid * 32 + qm;
        u16* op = ctx + (rowb + row) * 768 + h * 64 + l31;
        op[0]  = f2bf(oacc[0][r] * ir);
        op[32] = f2bf(oacc[1][r] * ir);
    }
}

// ---------------------------------------------------------------------------
extern "C" void kernel_launch(void* const* d_in, const int* in_sizes, int n_in,
                              void* d_out, int out_size, void* d_ws, size_t ws_size,
                              hipStream_t stream) {
    const float* x      = (const float*)d_in[0];
    const float* ln1_s  = (const float*)d_in[2];
    const float* ln1_b  = (const float*)d_in[3];
    const float* w_attn = (const float*)d_in[4];
    const float* b_attn = (const float*)d_in[5];
    const float* w_o    = (const float*)d_in[6];
    const float* b_o    = (const float*)d_in[7];
    const float* ln2_s  = (const float*)d_in[8];
    const float* ln2_b  = (const float*)d_in[9];
    const float* w_fc   = (const float*)d_in[10];
    const float* b_fc   = (const float*)d_in[11];
    const float* w_proj = (const float*)d_in[12];
    const float* b_proj = (const float*)d_in[13];

    char* ws = (char*)d_ws;
    u16* wT_attn = (u16*)(ws + 0);           // [2304][768]
    u16* wT_o    = (u16*)(ws + 3538944);     // [768][768]
    u16* wT_fc   = (u16*)(ws + 4718592);     // [3072][768]
    u16* wT_proj = (u16*)(ws + 9437184);     // [768][3072]
    u16* bufA    = (u16*)(ws + 14155776);    // bf16 [8192][768] (h / ctx / h2)
    u16* qbuf    = (u16*)(ws + 26738688);    // [48][2048][64]
    u16* kbuf    = (u16*)(ws + 39321600);    // [48][2048][64]
    u16* vbuf    = (u16*)(ws + 51904512);    // [48][64][2048]
    u16* act     = (u16*)(ws + 26738688);    // bf16 [8192][3072] (after attn)
    u16* x1b     = (u16*)(ws + 77070336);    // bf16 [8192][768] residual stream

    // fused transpose (6912 blocks) + LN1 (8192 blocks)
    pre_kernel<<<15104, 256, 0, stream>>>(w_attn, wT_attn, w_o, wT_o, w_fc, wT_fc,
                                          w_proj, wT_proj, x, ln1_s, ln1_b, bufA);
    gemm_kernel<0, 0, 0, 2, 128><<<dim3(64, 18), 256, 0, stream>>>(bufA, wT_attn, b_attn, nullptr, nullptr,
                                                                   8192, 2304, 768, qbuf, kbuf, vbuf);
    attn_kernel<<<1536, 128, 0, stream>>>(qbuf, kbuf, vbuf, bufA);
    // x1b = ctx @ w_o + b_o + x   (bf16 residual stream)
    gemm_kernel<0, 1, 0, 1, 64><<<dim3(128, 6), 256, 0, stream>>>(bufA, wT_o, b_o, x, x1b,
                                                                  8192, 768, 768, nullptr, nullptr, nullptr);
    ln_bf16_kernel<<<8192, 256, 0, stream>>>(x1b, ln2_s, ln2_b, bufA);
    // FC: 256^2 counted-vmcnt GEMM, GELU, bf16 out
    gemm256_kernel<1><<<dim3(32, 12), 512, 0, stream>>>(bufA, wT_fc, b_fc, act, 8192, 3072, 768);
    // d_out = act @ w_proj + b_proj + x1b
    gemm_kernel<0, 1, 1, 0, 64><<<dim3(128, 6), 256, 0, stream>>>(act, wT_proj, b_proj, x1b, (float*)d_out,
                                                                  8192, 768, 3072, nullptr, nullptr, nullptr);
}

// Round 18
// 252.451 us; speedup vs baseline: 1.0244x; 1.0244x over previous
//
#include <hip/hip_runtime.h>

// ---------------------------------------------------------------------------
// GPT-2 block: [transpose+LN1 fused] -> QKV GEMM (scatter q/k/vT) -> causal
// flash attn -> proj+res -> LN2 -> FC+GELU -> proj+res
// B=4 T=2048 C=768 H=12 HD=64. MFMA bf16, fp32 accum.
// CHAMPION (r16, 252.6 us): GEMMs 2-phase dbuf (BM 128/64, setprio, packed
// v-scatter), bf16 residual stream; attn swapped-QK^T 32x32, K/V LDS dbuf
// via global_load_lds, online-max + defer-rescale softmax, MFMA row-sums,
// setprio, 128-thr blocks, heavy-tiles-first.
// ---------------------------------------------------------------------------

typedef unsigned short u16;
typedef unsigned int u32;
typedef __attribute__((ext_vector_type(8))) short short8;   // 8 bf16 = 4 VGPR
typedef __attribute__((ext_vector_type(4))) float f32x4;
typedef __attribute__((ext_vector_type(16))) float f32x16;  // 32x32 MFMA C/D

__device__ __forceinline__ u16 f2bf(float f) {
    union { float f; unsigned u; } v; v.f = f;
    unsigned u = v.u;
    unsigned r = (u + 0x7FFFu + ((u >> 16) & 1u)) >> 16;
    return (u16)r;
}
__device__ __forceinline__ float bf2f(u16 h) {
    union { u32 u; float f; } v; v.u = ((u32)h) << 16;
    return v.f;
}

__device__ __forceinline__ u32 cvtpk_bf16(float lo, float hi) {
    u32 r;
    asm("v_cvt_pk_bf16_f32 %0, %1, %2" : "=v"(r) : "v"(lo), "v"(hi));
    return r;
}

// async global->LDS, 16B per lane. dest must be wave-uniform base + lane*16.
__device__ __forceinline__ void gld16(const u16* g, u16* l) {
    __builtin_amdgcn_global_load_lds(
        (const __attribute__((address_space(1))) void*)g,
        (__attribute__((address_space(3))) void*)l, 16, 0, 0);
}

// gelu_tanh(v) = v * sigmoid(2*0.79788456*(v + 0.044715 v^3))
__device__ __forceinline__ float gelu_fast(float v) {
    float t = v * v;
    float z2n = v * (-2.3022078f - 0.10294376f * t);   // -2z*log2(e)
    float e = __builtin_amdgcn_exp2f(z2n);             // e^{-2z}
    return v * __builtin_amdgcn_rcpf(1.0f + e);
}

// ---------------------------------------------------------------------------
// LayerNorm core: 3 values/thread -> bf16 out, 256 threads.
// ---------------------------------------------------------------------------
__device__ __forceinline__ void ln_core(float v0, float v1, float v2,
                                        const float* __restrict__ s,
                                        const float* __restrict__ b,
                                        u16* __restrict__ orow,
                                        float* red, int tid) {
    float sum = v0 + v1 + v2;
    float sq = v0 * v0 + v1 * v1 + v2 * v2;
#pragma unroll
    for (int off = 32; off; off >>= 1) {
        sum += __shfl_down(sum, off);
        sq += __shfl_down(sq, off);
    }
    int wid = tid >> 6, lane = tid & 63;
    if (lane == 0) { red[wid] = sum; red[4 + wid] = sq; }
    __syncthreads();
    if (tid == 0) {
        float s4 = red[0] + red[1] + red[2] + red[3];
        float q4 = red[4] + red[5] + red[6] + red[7];
        red[0] = s4 * (1.0f / 768.0f);
        red[1] = q4 * (1.0f / 768.0f);
    }
    __syncthreads();
    float mean = red[0];
    float var = red[1] - mean * mean;
    float rstd = rsqrtf(var + 1e-5f);
    orow[tid]       = f2bf((v0 - mean) * rstd * s[tid]       + b[tid]);
    orow[tid + 256] = f2bf((v1 - mean) * rstd * s[tid + 256] + b[tid + 256]);
    orow[tid + 512] = f2bf((v2 - mean) * rstd * s[tid + 512] + b[tid + 512]);
}

// ---------------------------------------------------------------------------
// Fused: weight transpose+convert (blocks [0,6912)) + LN1 (blocks [6912,15104)).
// ---------------------------------------------------------------------------
__global__ void pre_kernel(const float* __restrict__ w_attn, u16* __restrict__ wT_attn,
                           const float* __restrict__ w_o,    u16* __restrict__ wT_o,
                           const float* __restrict__ w_fc,   u16* __restrict__ wT_fc,
                           const float* __restrict__ w_proj, u16* __restrict__ wT_proj,
                           const float* __restrict__ x, const float* __restrict__ ln1_s,
                           const float* __restrict__ ln1_b, u16* __restrict__ h) {
    __shared__ float t[32][33];
    __shared__ float red[8];
    int tile = blockIdx.x;
    int tid = threadIdx.x;
    if (tile >= 6912) {
        int row = tile - 6912;
        const float* xr = x + (size_t)row * 768;
        ln_core(xr[tid], xr[tid + 256], xr[tid + 512], ln1_s, ln1_b,
                h + (size_t)row * 768, red, tid);
        return;
    }
    const float* w; u16* wt; int N; int idx;
    if (tile < 1728)      { w = w_attn; wt = wT_attn; N = 2304; idx = tile; }
    else if (tile < 2304) { w = w_o;    wt = wT_o;    N = 768;  idx = tile - 1728; }
    else if (tile < 4608) { w = w_fc;   wt = wT_fc;   N = 3072; idx = tile - 2304; }
    else                  { w = w_proj; wt = wT_proj; N = 768;  idx = tile - 4608; }
    int K = (tile >= 4608) ? 3072 : 768;
    int nx = N / 32;
    int n0 = (idx % nx) * 32, k0 = (idx / nx) * 32;
    int tx = tid & 31, ty = tid >> 5;  // 32 x 8
#pragma unroll
    for (int i = 0; i < 4; i++)
        t[ty + 8 * i][tx] = w[(size_t)(k0 + ty + 8 * i) * N + n0 + tx];
    __syncthreads();
#pragma unroll
    for (int i = 0; i < 4; i++)
        wt[(size_t)(n0 + ty + 8 * i) * K + k0 + tx] = f2bf(t[tx][ty + 8 * i]);
}

// ---------------------------------------------------------------------------
// LN2: bf16 input [8192][768] -> bf16 out
// ---------------------------------------------------------------------------
__global__ void ln_bf16_kernel(const u16* __restrict__ x, const float* __restrict__ s,
                               const float* __restrict__ b, u16* __restrict__ out) {
    __shared__ float red[8];
    int row = blockIdx.x;
    int tid = threadIdx.x;
    const u16* xr = x + (size_t)row * 768;
    ln_core(bf2f(xr[tid]), bf2f(xr[tid + 256]), bf2f(xr[tid + 512]),
            s, b, out + (size_t)row * 768, red, tid);
}

// ---------------------------------------------------------------------------
// GEMM (r9/r14 structure): out = act(A @ Wt^T + bias [+ res])
// OUTMODE: 0 = fp32 out, 1 = bf16 out, 2 = QKV scatter. RESBF: res is bf16.
// BM = 128 (4x4 frags) or 64 (2x4). BN=128 BK=64. 256 thr = 4 waves.
// 2-phase dbuf: stage tile t+1, compute tile t, one __syncthreads per tile.
// ---------------------------------------------------------------------------
template <int GELU, int RES, int RESBF, int OUTMODE, int BM>
__global__ __launch_bounds__(256) void gemm_kernel(
    const u16* __restrict__ A, const u16* __restrict__ Wt,
    const float* __restrict__ bias, const void* __restrict__ res,
    void* __restrict__ out, int M, int N, int K,
    u16* __restrict__ qbuf, u16* __restrict__ kbuf, u16* __restrict__ vbuf) {
    constexpr int FM = BM / 32;          // m-frags per wave (4 or 2)
    constexpr int SA = BM / 32;          // A stage rounds (4 or 2)
    constexpr int WR = BM / 2;           // wave row stride
    __shared__ __align__(16) u16 lA[2][BM * 64];
    __shared__ __align__(16) u16 lB[2][128 * 64];
    int m0 = blockIdx.x * BM, n0 = blockIdx.y * 128;
    int tid = threadIdx.x;
    int wid = tid >> 6, lane = tid & 63;
    int wr = wid >> 1, wc = wid & 1;
    int l15 = lane & 15, lhi = lane >> 4;

    const u16* aptr[SA];
    const u16* bptr[4];
#pragma unroll
    for (int s = 0; s < SA; s++) {
        int u = s * 256 + tid;
        int row = u >> 3;
        int c8 = (u & 7) ^ (row & 7);
        aptr[s] = A + (size_t)(m0 + row) * K + c8 * 8;
    }
#pragma unroll
    for (int s = 0; s < 4; s++) {
        int u = s * 256 + tid;
        int row = u >> 3;
        int c8 = (u & 7) ^ (row & 7);
        bptr[s] = Wt + (size_t)(n0 + row) * K + c8 * 8;
    }

    f32x4 acc[FM][4];
#pragma unroll
    for (int i = 0; i < FM; i++)
#pragma unroll
        for (int j = 0; j < 4; j++) acc[i][j] = (f32x4)0.0f;

    // prologue: stage tile 0 into buffer 0
#pragma unroll
    for (int s = 0; s < SA; s++) gld16(aptr[s], &lA[0][(s * 256 + tid) * 8]);
#pragma unroll
    for (int s = 0; s < 4; s++) gld16(bptr[s], &lB[0][(s * 256 + tid) * 8]);
    __syncthreads();

    int KT = K >> 6;
    int cur = 0;
    for (int t = 0; t < KT; t++) {
        if (t + 1 < KT) {
            int ko = (t + 1) << 6;
#pragma unroll
            for (int s = 0; s < SA; s++) gld16(aptr[s] + ko, &lA[cur ^ 1][(s * 256 + tid) * 8]);
#pragma unroll
            for (int s = 0; s < 4; s++) gld16(bptr[s] + ko, &lB[cur ^ 1][(s * 256 + tid) * 8]);
        }
        short8 af[2][FM], bfr[2][4];
#pragma unroll
        for (int ks = 0; ks < 2; ks++) {
#pragma unroll
            for (int f = 0; f < FM; f++) {
                int ra = wr * WR + f * 16 + l15;
                af[ks][f] = *(const short8*)&lA[cur][ra * 64 + (((ks * 4 + lhi) ^ (ra & 7)) << 3)];
            }
#pragma unroll
            for (int f = 0; f < 4; f++) {
                int rb = wc * 64 + f * 16 + l15;
                bfr[ks][f] = *(const short8*)&lB[cur][rb * 64 + (((ks * 4 + lhi) ^ (rb & 7)) << 3)];
            }
        }
        __builtin_amdgcn_s_setprio(1);
#pragma unroll
        for (int ks = 0; ks < 2; ks++)
#pragma unroll
            for (int fm = 0; fm < FM; fm++)
#pragma unroll
                for (int fn = 0; fn < 4; fn++)
                    acc[fm][fn] = __builtin_amdgcn_mfma_f32_16x16x32_bf16(
                        af[ks][fm], bfr[ks][fn], acc[fm][fn], 0, 0, 0);
        __builtin_amdgcn_s_setprio(0);
        __syncthreads();   // drains vmcnt(0): next tile ready; buf[cur] reusable
        cur ^= 1;
    }

    if (OUTMODE == 2) {
        int region = n0 / 768;
#pragma unroll
        for (int fm = 0; fm < FM; fm++)
#pragma unroll
            for (int fn = 0; fn < 4; fn++) {
                int col = n0 + wc * 64 + fn * 16 + l15;
                float bv = bias[col];
                int c = col - region * 768;
                int h = c >> 6, d = c & 63;
                if (region == 2) {
                    // v: [bh][d][t] — 4 consecutive t per thread -> one 8B store
                    int row0 = m0 + wr * WR + fm * 16 + lhi * 4;
                    int bb = row0 >> 11, t0 = row0 & 2047;
                    size_t bh = (size_t)bb * 12 + h;
                    union { u16 a[4]; uint2 v; } pk;
#pragma unroll
                    for (int r = 0; r < 4; r++) pk.a[r] = f2bf(acc[fm][fn][r] + bv);
                    *(uint2*)(&vbuf[(bh * 64 + d) * 2048 + t0]) = pk.v;
                } else {
#pragma unroll
                    for (int r = 0; r < 4; r++) {
                        int row = m0 + wr * WR + fm * 16 + lhi * 4 + r;
                        int bb = row >> 11, t = row & 2047;
                        u16 val = f2bf(acc[fm][fn][r] + bv);
                        size_t bh = (size_t)bb * 12 + h;
                        if (region == 0) qbuf[(bh * 2048 + t) * 64 + d] = val;
                        else             kbuf[(bh * 2048 + t) * 64 + d] = val;
                    }
                }
            }
    } else {
#pragma unroll
        for (int fm = 0; fm < FM; fm++)
#pragma unroll
            for (int fn = 0; fn < 4; fn++) {
                int col = n0 + wc * 64 + fn * 16 + l15;
                float bv = bias[col];
#pragma unroll
                for (int r = 0; r < 4; r++) {
                    int row = m0 + wr * WR + fm * 16 + lhi * 4 + r;
                    float v = acc[fm][fn][r] + bv;
                    if (RES) {
                        if (RESBF) v += bf2f(((const u16*)res)[(size_t)row * N + col]);
                        else       v += ((const float*)res)[(size_t)row * N + col];
                    }
                    if (GELU) v = gelu_fast(v);
                    if (OUTMODE == 1)
                        ((u16*)out)[(size_t)row * N + col] = f2bf(v);
                    else
                        ((float*)out)[(size_t)row * N + col] = v;
                }
            }
    }
}

// ---------------------------------------------------------------------------
// Causal flash attention (r12/r14 structure): swapped-QK^T 32x32, 2-phase
// K/V staging, online-max softmax w/ defer-rescale, MFMA row-sums, setprio.
// 128 threads = 2 waves x 32 q-rows, QBLK=64, 1536 blocks.
// q/k: bf16 [bh][t][64]; vT: bf16 [bh][64][t]. ctx: bf16 [b*T][768].
// ---------------------------------------------------------------------------
__global__ __launch_bounds__(128) void attn_kernel(const u16* __restrict__ qbuf,
                                                   const u16* __restrict__ kbuf,
                                                   const u16* __restrict__ vbuf,
                                                   u16* __restrict__ ctx) {
    int bid = blockIdx.x;
    int qt = 31 - (bid / 48);        // heavy tiles first
    int bh = bid % 48;
    int b = bh / 12, h = bh % 12;
    int q0 = qt * 64;
    int tid = threadIdx.x, wid = tid >> 6, lane = tid & 63;
    int l31 = lane & 31, hi = lane >> 5;

    __shared__ __align__(16) u16 lK[2][64 * 64];   // [key][d] swizzled
    __shared__ __align__(16) u16 lV[2][64 * 64];   // [d][key] swizzled

    const size_t bhT = (size_t)bh * 2048;

    const u16* kp[4];
    const u16* vp[4];
#pragma unroll
    for (int s = 0; s < 4; s++) {
        int u = s * 128 + tid;
        int row = u >> 3;
        int c8 = (u & 7) ^ (row & 7);
        kp[s] = kbuf + (bhT + row) * 64 + c8 * 8;                    // + k0*64
        vp[s] = vbuf + ((size_t)bh * 64 + row) * 2048 + c8 * 8;      // + k0
    }

    // Q B-fragments: b[j] = Q[q=l31][d = ks*16 + 8*hi + j]
    int qrow = q0 + wid * 32 + l31;
    short8 bq[4];
#pragma unroll
    for (int ks = 0; ks < 4; ks++)
        bq[ks] = *(const short8*)(qbuf + (bhT + qrow) * 64 + ks * 16 + hi * 8);

    short8 ones;
#pragma unroll
    for (int j = 0; j < 8; j++) ones[j] = (short)0x3F80;  // bf16 1.0

    f32x16 oacc[2], sacc;
#pragma unroll
    for (int dt = 0; dt < 2; dt++) oacc[dt] = (f32x16)0.0f;
    sacc = (f32x16)0.0f;
    float mb = -1e30f;
    const float C2 = 0.125f * 1.44269504089f;
    const float THR = 11.55f;        // 8 nats in log2
    int myq = q0 + wid * 32 + l31;

    int nt = qt + 1;
#pragma unroll
    for (int s = 0; s < 4; s++) gld16(kp[s], &lK[0][(s * 128 + tid) * 8]);
#pragma unroll
    for (int s = 0; s < 4; s++) gld16(vp[s], &lV[0][(s * 128 + tid) * 8]);
    __syncthreads();

    int cur = 0;
    for (int t = 0; t < nt; t++) {
        int k0 = t * 64;
        if (t + 1 < nt) {
            int kn = (t + 1) * 64;
#pragma unroll
            for (int s = 0; s < 4; s++) gld16(kp[s] + (size_t)kn * 64, &lK[cur ^ 1][(s * 128 + tid) * 8]);
#pragma unroll
            for (int s = 0; s < 4; s++) gld16(vp[s] + kn, &lV[cur ^ 1][(s * 128 + tid) * 8]);
        }
        {
            f32x16 sa[2];
#pragma unroll
            for (int kt = 0; kt < 2; kt++) sa[kt] = (f32x16)0.0f;
            __builtin_amdgcn_s_setprio(1);
#pragma unroll
            for (int kt = 0; kt < 2; kt++) {
                int rk = kt * 32 + l31;
#pragma unroll
                for (int ks = 0; ks < 4; ks++) {
                    short8 ak = *(const short8*)&lK[cur][rk * 64 + (((ks * 2 + hi) ^ (rk & 7)) << 3)];
                    sa[kt] = __builtin_amdgcn_mfma_f32_32x32x16_bf16(ak, bq[ks], sa[kt], 0, 0, 0);
                }
            }
            __builtin_amdgcn_s_setprio(0);
            if (k0 + 63 > q0 + wid * 32) {
#pragma unroll
                for (int kt = 0; kt < 2; kt++)
#pragma unroll
                    for (int r = 0; r < 16; r++) {
                        int key = k0 + kt * 32 + (r & 3) + 8 * (r >> 2) + 4 * hi;
                        if (key > myq) sa[kt][r] = -1e30f;
                    }
            }
            float tmax = -1e30f;
#pragma unroll
            for (int kt = 0; kt < 2; kt++)
#pragma unroll
                for (int r = 0; r < 16; r += 2)
                    tmax = fmaxf(tmax, fmaxf(sa[kt][r], sa[kt][r + 1]));  // -> v_max3
            tmax = fmaxf(tmax, __shfl_xor(tmax, 32));
            float tmb = tmax * C2;
            if (__any(tmb > mb + THR)) {
                float mbn = fmaxf(mb, tmb);
                float corr = __builtin_amdgcn_exp2f(mb - mbn);
#pragma unroll
                for (int r = 0; r < 16; r++) {
                    int qm = (r & 3) + 8 * (r >> 2) + 4 * hi;
                    float c = __shfl(corr, qm);
                    oacc[0][r] *= c;
                    oacc[1][r] *= c;
                    sacc[r] *= c;
                }
                mb = mbn;
            }
#pragma unroll
            for (int kt = 0; kt < 2; kt++)
#pragma unroll
                for (int r = 0; r < 16; r++)
                    sa[kt][r] = __builtin_amdgcn_exp2f(fmaf(sa[kt][r], C2, -mb));
            short8 pa[4];
#pragma unroll
            for (int kt = 0; kt < 2; kt++)
#pragma unroll
                for (int ks2 = 0; ks2 < 2; ks2++) {
                    int base = ks2 * 8;
                    u32 A0 = cvtpk_bf16(sa[kt][base + 0], sa[kt][base + 1]);
                    u32 B0 = cvtpk_bf16(sa[kt][base + 4], sa[kt][base + 5]);
                    u32 A1 = cvtpk_bf16(sa[kt][base + 2], sa[kt][base + 3]);
                    u32 B1 = cvtpk_bf16(sa[kt][base + 6], sa[kt][base + 7]);
                    u32 A0s = (u32)__shfl_xor((int)A0, 32);
                    u32 B0s = (u32)__shfl_xor((int)B0, 32);
                    u32 A1s = (u32)__shfl_xor((int)A1, 32);
                    u32 B1s = (u32)__shfl_xor((int)B1, 32);
                    union { u32 u[4]; short8 s; } w;
                    w.u[0] = hi ? B0s : A0;
                    w.u[1] = hi ? B1s : A1;
                    w.u[2] = hi ? B0 : A0s;
                    w.u[3] = hi ? B1 : A1s;
                    pa[kt * 2 + ks2] = w.s;
                }
            __builtin_amdgcn_s_setprio(1);
#pragma unroll
            for (int kt = 0; kt < 2; kt++)
#pragma unroll
                for (int ks2 = 0; ks2 < 2; ks2++) {
                    short8 ap = pa[kt * 2 + ks2];
#pragma unroll
                    for (int dt = 0; dt < 2; dt++) {
                        int rd = dt * 32 + l31;
                        short8 bv = *(const short8*)&lV[cur][rd * 64 + (((kt * 4 + ks2 * 2 + hi) ^ (rd & 7)) << 3)];
                        oacc[dt] = __builtin_amdgcn_mfma_f32_32x32x16_bf16(ap, bv, oacc[dt], 0, 0, 0);
                    }
                    sacc = __builtin_amdgcn_mfma_f32_32x32x16_bf16(ap, ones, sacc, 0, 0, 0);
                }
            __builtin_amdgcn_s_setprio(0);
        }
        __syncthreads();
        cur ^= 1;
    }
    const size_t rowb = (size_t)b * 2048;
#pragma unroll
    for (int r = 0; r < 16; r++) {
        float ir = __builtin_amdgcn_rcpf(sacc[r]);
        int qm = (r & 3) + 8 * (r >> 2) + 4 * hi;
        int row = q0 + wid * 32 + qm;
        u16* op = ctx + (rowb + row) * 768 + h * 64 + l31;
        op[0]  = f2bf(oacc[0][r] * ir);
        op[32] = f2bf(oacc[1][r] * ir);
    }
}

// ---------------------------------------------------------------------------
extern "C" void kernel_launch(void* const* d_in, const int* in_sizes, int n_in,
                              void* d_out, int out_size, void* d_ws, size_t ws_size,
                              hipStream_t stream) {
    const float* x      = (const float*)d_in[0];
    const float* ln1_s  = (const float*)d_in[2];
    const float* ln1_b  = (const float*)d_in[3];
    const float* w_attn = (const float*)d_in[4];
    const float* b_attn = (const float*)d_in[5];
    const float* w_o    = (const float*)d_in[6];
    const float* b_o    = (const float*)d_in[7];
    const float* ln2_s  = (const float*)d_in[8];
    const float* ln2_b  = (const float*)d_in[9];
    const float* w_fc   = (const float*)d_in[10];
    const float* b_fc   = (const float*)d_in[11];
    const float* w_proj = (const float*)d_in[12];
    const float* b_proj = (const float*)d_in[13];

    char* ws = (char*)d_ws;
    u16* wT_attn = (u16*)(ws + 0);           // [2304][768]
    u16* wT_o    = (u16*)(ws + 3538944);     // [768][768]
    u16* wT_fc   = (u16*)(ws + 4718592);     // [3072][768]
    u16* wT_proj = (u16*)(ws + 9437184);     // [768][3072]
    u16* bufA    = (u16*)(ws + 14155776);    // bf16 [8192][768] (h / ctx / h2)
    u16* qbuf    = (u16*)(ws + 26738688);    // [48][2048][64]
    u16* kbuf    = (u16*)(ws + 39321600);    // [48][2048][64]
    u16* vbuf    = (u16*)(ws + 51904512);    // [48][64][2048]
    u16* act     = (u16*)(ws + 26738688);    // bf16 [8192][3072] (after attn)
    u16* x1b     = (u16*)(ws + 77070336);    // bf16 [8192][768] residual stream

    // fused transpose (6912 blocks) + LN1 (8192 blocks)
    pre_kernel<<<15104, 256, 0, stream>>>(w_attn, wT_attn, w_o, wT_o, w_fc, wT_fc,
                                          w_proj, wT_proj, x, ln1_s, ln1_b, bufA);
    gemm_kernel<0, 0, 0, 2, 128><<<dim3(64, 18), 256, 0, stream>>>(bufA, wT_attn, b_attn, nullptr, nullptr,
                                                                   8192, 2304, 768, qbuf, kbuf, vbuf);
    attn_kernel<<<1536, 128, 0, stream>>>(qbuf, kbuf, vbuf, bufA);
    // x1b = ctx @ w_o + b_o + x   (bf16 residual stream)
    gemm_kernel<0, 1, 0, 1, 64><<<dim3(128, 6), 256, 0, stream>>>(bufA, wT_o, b_o, x, x1b,
                                                                  8192, 768, 768, nullptr, nullptr, nullptr);
    ln_bf16_kernel<<<8192, 256, 0, stream>>>(x1b, ln2_s, ln2_b, bufA);
    gemm_kernel<1, 0, 0, 1, 128><<<dim3(64, 24), 256, 0, stream>>>(bufA, wT_fc, b_fc, nullptr, act,
                                                                   8192, 3072, 768, nullptr, nullptr, nullptr);
    // d_out = act @ w_proj + b_proj + x1b
    gemm_kernel<0, 1, 1, 0, 64><<<dim3(128, 6), 256, 0, stream>>>(act, wT_proj, b_proj, x1b, (float*)d_out,
                                                                  8192, 768, 3072, nullptr, nullptr, nullptr);
}